// Round 7
// baseline (151.692 us; speedup 1.0000x reference)
//
#include <hip/hip_runtime.h>
#include <hip/hip_bf16.h>
#include <stdint.h>

// Problem constants: T=512, B=32, I=512, H=512
#define T_DIM 512
#define B_DIM 32
#define K_DIM 512     // I
#define H_DIM 512
#define N_DIM 1536    // 3*H, gate-packed in h-pairs: n = (h>>1)*6 + (h&1)*3 + g
#define M_DIM 16384   // T*B

typedef __bf16 bf16_t;
typedef bf16_t bf16x8 __attribute__((ext_vector_type(8)));
typedef float floatx4 __attribute__((ext_vector_type(4)));

#define LOG2E 1.442695041f     // 1/ln(2)
#define TWO_LOG2E 2.885390082f

// ---------- fp32 -> bf16 (RNE), 8 elems/thread, both inputs fused ----------
__device__ __forceinline__ unsigned int f2bf_bits(float f) {
  uint32_t u = __builtin_bit_cast(uint32_t, f);
  u += 0x7FFFu + ((u >> 16) & 1u);
  return u >> 16;
}

__global__ void convert_both_kernel(const float* __restrict__ x,
                                    unsigned short* __restrict__ xb,
                                    const float* __restrict__ W,
                                    unsigned short* __restrict__ Wb) {
  int bid = blockIdx.x;
  const float* src;
  unsigned short* dst;
  int i;
  if (bid < 4096) {           // x: 8388608 elems, identity convert
    i = (bid * 256 + threadIdx.x) * 8;
    src = x + i;
    dst = xb + i;
  } else {                    // Wb: 1536 rows x 512, h-pair permuted
    i = ((bid - 4096) * 256 + threadIdx.x) * 8;
    int n = i >> 9;           // packed row
    int k = i & 511;
    int p6 = n / 6;
    int sub = n - p6 * 6;
    int hodd = (sub >= 3) ? 1 : 0;
    int g = sub - hodd * 3;
    int h = p6 * 2 + hodd;
    src = W + ((g << 9) + h) * 512 + k;
    dst = Wb + i;
  }
  const float4* p = (const float4*)src;
  float4 f0 = p[0];
  float4 f1 = p[1];
  uint4 v;
  v.x = f2bf_bits(f0.x) | (f2bf_bits(f0.y) << 16);
  v.y = f2bf_bits(f0.z) | (f2bf_bits(f0.w) << 16);
  v.z = f2bf_bits(f1.x) | (f2bf_bits(f1.y) << 16);
  v.w = f2bf_bits(f1.z) | (f2bf_bits(f1.w) << 16);
  *(uint4*)dst = v;
}

// ---------- bf16 GEMM: NT, 256x384 tile, BK=64, XOR-swizzled LDS ----------
// R14 theory: staging RATE is pinned (~12.6 B/cy/CU across 3 structures
// R5/R1/R6 all 37-42us); the controllable term is staged VOLUME
//   = M*K*2*(N/BN) + N*K*2*(M/BM)  -- pure tile geometry.
// BM=256, BN=384 -> grid 64x4 = 256 blocks = EXACTLY 1/CU, one round,
// zero tail; volume 288 -> 164 MB (-43%). Proven 2-barrier structure
// (stage -> sync -> MFMA -> sync), BK=64 (8 iters), single 80KB buffer.
// 8 waves 2M x 4N, wave tile 128x96, acc[8][6] = 192 VGPR;
// __launch_bounds__(512,2) caps VGPR at 256 (8 waves/CU).
// Kept: T1 XCD/A-band-major swizzle (per XCD: 8 A-bands 2MB + B 1.5MB
// < 4MB L2); 16B-chunk XOR LDS swizzle both sides (rule #21).
__global__ __launch_bounds__(512, 2) void gemm_bf16_kernel(
    const unsigned short* __restrict__ A, const unsigned short* __restrict__ Bm,
    _Float16* __restrict__ C) {
  __shared__ bf16_t smem[40960];  // [0..16383] A 256x64 | [16384..] B 384x64
  const int tid = threadIdx.x;
  const int lane = tid & 63;
  const int w = tid >> 6;
  // XCD-chunked, A-band-major block swizzle (bijective: 256 = 8*32)
  const int id = blockIdx.x;                  // 0..255
  const int swz = (id & 7) * 32 + (id >> 3);
  const int mIdx = swz >> 2;                  // 0..63
  const int nIdx = swz & 3;                   // 0..3
  const int tileM = mIdx * 256;
  const int tileN = nIdx * 384;
  const int waveM = w >> 2;                   // 0..1
  const int waveN = w & 3;                    // 0..3
  const int lm = lane & 15;
  const int lg = lane >> 4;                   // 0..3 k-chunk group

  floatx4 acc[8][6] = {};

  for (int k0 = 0; k0 < K_DIM; k0 += 64) {
    // A: 2048 16B chunks (256 rows x 8), 4 groups of 512
#pragma unroll
    for (int g = 0; g < 4; ++g) {
      int s = g * 512 + tid;
      int row = s >> 3;
      int kc = (s & 7) ^ (row & 7);  // source chunk under swizzle
      bf16_t* la = smem + (g * 512 + w * 64) * 8;
      const unsigned short* ga = A + (size_t)(tileM + row) * K_DIM + k0 + kc * 8;
      __builtin_amdgcn_global_load_lds(
          (const __attribute__((address_space(1))) unsigned int*)ga,
          (__attribute__((address_space(3))) unsigned int*)la, 16, 0, 0);
    }
    // B: 3072 chunks (384 rows x 8), 6 groups of 512
#pragma unroll
    for (int g = 0; g < 6; ++g) {
      int s = g * 512 + tid;
      int row = s >> 3;
      int kc = (s & 7) ^ (row & 7);
      bf16_t* lb = smem + 16384 + (g * 512 + w * 64) * 8;
      const unsigned short* gb = Bm + (size_t)(tileN + row) * K_DIM + k0 + kc * 8;
      __builtin_amdgcn_global_load_lds(
          (const __attribute__((address_space(1))) unsigned int*)gb,
          (__attribute__((address_space(3))) unsigned int*)lb, 16, 0, 0);
    }
    __syncthreads();

#pragma unroll
    for (int ks = 0; ks < 2; ++ks) {
      bf16x8 bfg[6];
      const int c = ks * 4 + lg;
#pragma unroll
      for (int j = 0; j < 6; ++j) {
        int row = waveN * 96 + j * 16 + lm;
        bfg[j] = *(const bf16x8*)(smem + 16384 + row * 64 + ((c ^ (row & 7)) << 3));
      }
#pragma unroll
      for (int i = 0; i < 8; ++i) {
        int row = waveM * 128 + i * 16 + lm;
        bf16x8 af = *(const bf16x8*)(smem + row * 64 + ((c ^ (row & 7)) << 3));
#pragma unroll
        for (int j = 0; j < 6; ++j)
          acc[i][j] = __builtin_amdgcn_mfma_f32_16x16x32_bf16(af, bfg[j],
                                                              acc[i][j], 0, 0, 0);
      }
    }
    __syncthreads();  // also guarantees smem reusable for the epilogue
  }

  // Epilogue. MFMA C/D layout: col=lane&15 (+16j), row=(lane>>4)*4+reg (+16i).
  // 4 passes of 32 rows through a 32x100-strided wave-private LDS region
  // (stride 100 fp16 = 50 dw == 18 mod 32 banks: rows spread across banks),
  // read back as uint2 -> 8B/lane contiguous row chunks.
  _Float16* ep = (_Float16*)smem + w * 3200;  // 32x100 fp16 per wave
  const size_t crow0 = (size_t)(tileM + waveM * 128);
  const int ccol0 = tileN + waveN * 96;
#pragma unroll
  for (int p = 0; p < 4; ++p) {
#pragma unroll
    for (int ih = 0; ih < 2; ++ih) {
      const int i = 2 * p + ih;
#pragma unroll
      for (int j = 0; j < 6; ++j) {
        const int cl = lm + j * 16;
        const int sub = (ccol0 + cl) % 6;
        const float scl = (sub == 2 || sub == 5) ? TWO_LOG2E : -LOG2E;
#pragma unroll
        for (int r = 0; r < 4; ++r) {
          int rl = (lane >> 4) * 4 + r + 16 * ih;  // 0..31
          ep[rl * 100 + cl] = (_Float16)(scl * acc[i][j][r]);
        }
      }
    }
    // wave-private region: DS ops within a wave are ordered; no barrier
    // 32 rows x 24 uint2 (96 cols) = 768 u2, 64 lanes -> 12 rounds
#pragma unroll
    for (int rnd = 0; rnd < 12; ++rnd) {
      int idx = rnd * 64 + lane;
      int row = idx / 24;
      int cu = idx - row * 24;
      uint2 v = *(const uint2*)(ep + row * 100 + cu * 4);
      *(uint2*)(C + (crow0 + p * 32 + row) * N_DIM + ccol0 + cu * 4) = v;
    }
  }
}

// ---------- diagonal GRU scan (unchanged) ----------
__global__ __launch_bounds__(64) void indgru_scan_kernel(
    const _Float16* __restrict__ gx, const float* __restrict__ h0,
    const float* __restrict__ w_hh, float* __restrict__ out,
    float* __restrict__ hlast) {
  const int idx = blockIdx.x * 64 + threadIdx.x;  // 0..16383
  const int b = idx >> 9;
  const int h = idx & (H_DIM - 1);
  const float wr = -LOG2E * w_hh[h];
  const float wz = -LOG2E * w_hh[H_DIM + h];
  const float wn = TWO_LOG2E * w_hh[2 * H_DIM + h];
  const int sh = (h & 1) << 4;  // funnel shift: 0 or 16 bits
  float hv = h0[idx];

  const char* base = (const char*)(gx + (size_t)b * N_DIM + (h >> 1) * 6) + ((h & 1) << 2);
  float* outp = out + (size_t)b * H_DIM + h;  // t-stride 16384 fp32

  constexpr int D = 32;
  constexpr size_t TSTRIDE = (size_t)B_DIM * N_DIM * sizeof(_Float16);  // 98304 B
  uint2 pq[D];
#pragma unroll
  for (int t = 0; t < D; ++t)
    pq[t] = *(const uint2*)(base + (size_t)t * TSTRIDE);

  auto cvt16 = [](uint32_t bits) {
    return (float)__builtin_bit_cast(_Float16, (unsigned short)bits);
  };

  for (int t0 = 0; t0 < T_DIM - D; t0 += D) {
#pragma unroll
    for (int s = 0; s < D; ++s) {
      const int t = t0 + s;
      uint2 qv = pq[s];
      pq[s] = *(const uint2*)(base + (size_t)(t + D) * TSTRIDE);
      asm volatile("" ::: "memory");  // pin prefetch distance
      uint64_t v = (((uint64_t)qv.y << 32) | qv.x) >> sh;
      float gr = cvt16((uint32_t)v);
      float gz = cvt16((uint32_t)(v >> 16));
      float gn = cvt16((uint32_t)(v >> 32));
      float ar = fmaf(wr, hv, gr);
      float az = fmaf(wz, hv, gz);
      float t1 = wn * hv;
      float er = __builtin_amdgcn_exp2f(ar);
      float ez = __builtin_amdgcn_exp2f(az);
      float r = __builtin_amdgcn_rcpf(1.0f + er);
      float z = __builtin_amdgcn_rcpf(1.0f + ez);
      float en = __builtin_amdgcn_exp2f(fmaf(r, t1, gn));
      float u = __builtin_amdgcn_rcpf(1.0f + en);
      float n = fmaf(-2.0f, u, 1.0f);
      float zh = z * hv;
      float omz = 1.0f - z;
      hv = fmaf(n, omz, zh);
      outp[(size_t)t * (B_DIM * H_DIM)] = hv;
    }
  }
#pragma unroll
  for (int s = 0; s < D; ++s) {
    const int t = T_DIM - D + s;
    uint2 qv = pq[s];
    uint64_t v = (((uint64_t)qv.y << 32) | qv.x) >> sh;
    float gr = cvt16((uint32_t)v);
    float gz = cvt16((uint32_t)(v >> 16));
    float gn = cvt16((uint32_t)(v >> 32));
    float ar = fmaf(wr, hv, gr);
    float az = fmaf(wz, hv, gz);
    float t1 = wn * hv;
    float er = __builtin_amdgcn_exp2f(ar);
    float ez = __builtin_amdgcn_exp2f(az);
    float r = __builtin_amdgcn_rcpf(1.0f + er);
    float z = __builtin_amdgcn_rcpf(1.0f + ez);
    float en = __builtin_amdgcn_exp2f(fmaf(r, t1, gn));
    float u = __builtin_amdgcn_rcpf(1.0f + en);
    float n = fmaf(-2.0f, u, 1.0f);
    float zh = z * hv;
    float omz = 1.0f - z;
    hv = fmaf(n, omz, zh);
    outp[(size_t)t * (B_DIM * H_DIM)] = hv;
  }
  hlast[idx] = hv;
}

extern "C" void kernel_launch(void* const* d_in, const int* in_sizes, int n_in,
                              void* d_out, int out_size, void* d_ws, size_t ws_size,
                              hipStream_t stream) {
  const float* x    = (const float*)d_in[0];   // (T,B,I)  = 8388608
  const float* h0   = (const float*)d_in[1];   // (B,H)    = 16384
  const float* W_ih = (const float*)d_in[2];   // (3H,I)   = 786432
  const float* w_hh = (const float*)d_in[3];   // (3,H)    = 1536

  float* out = (float*)d_out;                          // (T,B,H)
  float* hlast = out + (size_t)T_DIM * B_DIM * H_DIM;  // (1,B,H)

  // workspace: xb(bf16) 16 MB | Wb(bf16 1536x512) 1.5 MB | gx(fp16) 50 MB
  char* ws = (char*)d_ws;
  unsigned short* xb = (unsigned short*)ws;
  unsigned short* Wb = (unsigned short*)(ws + 16777216);
  _Float16* gx = (_Float16*)(ws + 16777216 + 1572864);

  convert_both_kernel<<<4480, 256, 0, stream>>>(x, xb, W_ih, Wb);

  gemm_bf16_kernel<<<256, 512, 0, stream>>>(xb, Wb, gx);

  indgru_scan_kernel<<<256, 64, 0, stream>>>(gx, h0, w_hh, out, hlast);
}